// Round 3
// baseline (113.248 us; speedup 1.0000x reference)
//
#include <hip/hip_runtime.h>

#define BB 16
#define NN 4096
#define MM 4096
#define TPB 256
#define KX 8
#define MSPLIT 8
#define CH (NN / MSPLIT) /* 512 database points per block */

// ---------------------------------------------------------------------------
// Pack X as float4(x,y,z,|p|^2); transform target by T (row-vector convention,
// p' = [p,1] @ T, w-divide) and pack the same way.
// ---------------------------------------------------------------------------
__global__ __launch_bounds__(TPB) void prep_kernel(
    const float* __restrict__ Xv, const float* __restrict__ Yv,
    const float* __restrict__ Tm,
    float4* __restrict__ xbuf, float4* __restrict__ ybuf)
{
  int idx = blockIdx.x * TPB + threadIdx.x;
  if (idx < BB * NN) {
    float x0 = Xv[idx * 3 + 0], x1 = Xv[idx * 3 + 1], x2 = Xv[idx * 3 + 2];
    xbuf[idx] = make_float4(x0, x1, x2, x0 * x0 + x1 * x1 + x2 * x2);
  } else {
    int j = idx - BB * NN;          // b*MM + m
    int b = j / MM;
    const float* T = Tm + b * 16;   // row-major [4][4]
    float y0 = Yv[j * 3 + 0], y1 = Yv[j * 3 + 1], y2 = Yv[j * 3 + 2];
    float t0 = y0 * T[0] + y1 * T[4] + y2 * T[8]  + T[12];
    float t1 = y0 * T[1] + y1 * T[5] + y2 * T[9]  + T[13];
    float t2 = y0 * T[2] + y1 * T[6] + y2 * T[10] + T[14];
    float t3 = y0 * T[3] + y1 * T[7] + y2 * T[11] + T[15];
    t0 /= t3; t1 /= t3; t2 /= t3;
    ybuf[j] = make_float4(t0, t1, t2, t0 * t0 + t1 * t1 + t2 * t2);
  }
}

// ---------------------------------------------------------------------------
// One kernel does both chamfer directions: blockIdx.z in [0,2B).
//   z <  B : queries = X points,  database = transformed targets
//   z >= B : queries = targets,   database = X points
// Each thread owns KX query points; database chunk (CH pts) staged in LDS and
// broadcast-read. Inner op: t = fma(-2qx,Yx, fma(-2qy,Yy, fma(-2qz,Yz, sy)));
// rmin = min(rmin, t)  -> 4 VALU per pair. Clamped result combined across
// MSPLIT database chunks via atomicMin on float bits (valid for values >= 0).
// ---------------------------------------------------------------------------
__global__ __launch_bounds__(TPB) void minpass_kernel(
    const float4* __restrict__ xbuf, const float4* __restrict__ ybuf,
    unsigned* __restrict__ rminA, unsigned* __restrict__ rminB)
{
  __shared__ float4 tile[CH];
  int z = blockIdx.z;
  const float4* q; const float4* db; unsigned* r;
  if (z < BB) {
    q = xbuf + (size_t)z * NN; db = ybuf + (size_t)z * MM; r = rminA + (size_t)z * NN;
  } else {
    int b = z - BB;
    q = ybuf + (size_t)b * MM; db = xbuf + (size_t)b * NN; r = rminB + (size_t)b * MM;
  }
  db += (size_t)blockIdx.y * CH;

  for (int i = threadIdx.x; i < CH; i += TPB) tile[i] = db[i];
  __syncthreads();

  int qoff = blockIdx.x * (TPB * KX) + threadIdx.x;

  float nx[KX], ny[KX], nz[KX], qs[KX], rm[KX];
#pragma unroll
  for (int k = 0; k < KX; k++) {
    float4 p = q[qoff + k * TPB];
    nx[k] = -2.f * p.x; ny[k] = -2.f * p.y; nz[k] = -2.f * p.z;
    qs[k] = p.w;
    rm[k] = 1e30f;
  }

#pragma unroll 4
  for (int j = 0; j < CH; j++) {
    float4 Y = tile[j];
#pragma unroll
    for (int k = 0; k < KX; k++) {
      float t = fmaf(nz[k], Y.z, Y.w);
      t = fmaf(ny[k], Y.y, t);
      t = fmaf(nx[k], Y.x, t);
      rm[k] = fminf(rm[k], t);
    }
  }

#pragma unroll
  for (int k = 0; k < KX; k++) {
    float d = fmaxf(qs[k] + rm[k], 0.f);            // clamp => nonneg => uint-ordered
    atomicMin(r + qoff + k * TPB, __float_as_uint(d));
  }
}

// ---------------------------------------------------------------------------
// Sum all 2*B*N row-mins into d_out[0].
// ---------------------------------------------------------------------------
__global__ __launch_bounds__(TPB) void reduce_kernel(
    const float* __restrict__ v, float* __restrict__ out, int n)
{
  __shared__ float wsum[TPB / 64];
  float s = 0.f;
  for (int i = blockIdx.x * TPB + threadIdx.x; i < n; i += gridDim.x * TPB)
    s += v[i];
#pragma unroll
  for (int o = 32; o > 0; o >>= 1) s += __shfl_down(s, o, 64);
  int wid = threadIdx.x >> 6, lane = threadIdx.x & 63;
  if (lane == 0) wsum[wid] = s;
  __syncthreads();
  if (threadIdx.x == 0) {
    float t = 0.f;
#pragma unroll
    for (int w = 0; w < TPB / 64; w++) t += wsum[w];
    atomicAdd(out, t);
  }
}

extern "C" void kernel_launch(void* const* d_in, const int* in_sizes, int n_in,
                              void* d_out, int out_size, void* d_ws, size_t ws_size,
                              hipStream_t stream) {
  const float* Xv = (const float*)d_in[0];   // [B,N,3]
  const float* Yv = (const float*)d_in[1];   // [B,M,3]
  const float* Tm = (const float*)d_in[2];   // [B,4,4]
  float* out = (float*)d_out;

  char* ws = (char*)d_ws;
  float4*   xbuf = (float4*)ws;                                   // B*N*16 = 1 MB
  float4*   ybuf = (float4*)(ws + (size_t)BB * NN * 16);          // B*M*16 = 1 MB
  unsigned* rmin = (unsigned*)(ws + (size_t)BB * (NN + MM) * 16); // B*(N+M)*4 = 512 KB

  // init: row-min buffer to large float (0x7F7F7F7F ~ 3.4e38), output to 0
  hipMemsetAsync(rmin, 0x7F, (size_t)BB * (NN + MM) * 4, stream);
  hipMemsetAsync(out, 0, sizeof(float), stream);

  prep_kernel<<<(BB * (NN + MM)) / TPB, TPB, 0, stream>>>(Xv, Yv, Tm, xbuf, ybuf);

  dim3 grid(NN / (TPB * KX), MSPLIT, 2 * BB);   // (2, 8, 32) = 512 blocks
  minpass_kernel<<<grid, TPB, 0, stream>>>(xbuf, ybuf, rmin, rmin + (size_t)BB * NN);

  reduce_kernel<<<256, TPB, 0, stream>>>((const float*)rmin, out, BB * (NN + MM));
}

// Round 4
// 96.250 us; speedup vs baseline: 1.1766x; 1.1766x over previous
//
#include <hip/hip_runtime.h>
#include <hip/hip_bf16.h>

#define BBATCH 16
#define NPTS   4096
#define NTOTAL (BBATCH*NPTS)            /* 65536 points per side */
#define ROWS_PER_BLOCK 128              /* 4 waves x 32 rows */
#define NCHUNKS (NPTS/ROWS_PER_BLOCK)   /* 32 n-chunks per batch */
#define MCHUNK 512                      /* m points staged in LDS per round */
#define NMCHUNKS (NPTS/MCHUNK)          /* 8 */
#define TILES (MCHUNK/32)               /* 16 MFMA col-tiles per chunk */

typedef unsigned int  uint_t;
typedef unsigned short ushort_t;
typedef __attribute__((ext_vector_type(8)))  short bf16x8;
typedef __attribute__((ext_vector_type(16))) float f32x16;

__device__ __forceinline__ ushort_t bfh(float v) {
  union { __hip_bfloat16 h; ushort_t u; } c; c.h = __float2bfloat16(v); return c.u;
}
__device__ __forceinline__ float bff(ushort_t u) {
  union { ushort_t u; __hip_bfloat16 h; } c; c.u = u; return __bfloat162float(c.h);
}

// ---------------------------------------------------------------------------
// prep: build packed K=16 bf16 records so that one mfma_32x32x16_bf16 yields
// full squared distances:  dot(A_n, B_m) = sx + sy - 2 x.y   (13 used slots)
//   A = [xh0..2, xl0..2, xh0..2, sxh, sxl, 1, 1, 0,0,0]
//   B = [zh0..2, zh0..2, zl0..2, 1, 1, syh, syl, 0,0,0],  z = -2*(y @ T)
// Also initializes colminG (+INF pattern) and out (0).
// ---------------------------------------------------------------------------
__global__ __launch_bounds__(256) void prep(
    const float* __restrict__ Xv, const float* __restrict__ Yv,
    const float* __restrict__ Tm,
    ushort_t* __restrict__ Apack, ushort_t* __restrict__ Bpack,
    uint_t* __restrict__ colminG, float* __restrict__ out)
{
  int idx = blockIdx.x * 256 + threadIdx.x;
  if (idx < NTOTAL) colminG[idx] = 0x7F7F7F7Fu;
  if (idx == 0) out[0] = 0.f;

  union { ushort_t r[16]; uint4 q[2]; } u;
  const ushort_t ONE = 0x3F80;

  if (idx < NTOTAL) {
    float x0 = Xv[idx*3], x1 = Xv[idx*3+1], x2 = Xv[idx*3+2];
    float sx = x0*x0 + x1*x1 + x2*x2;
    ushort_t h0=bfh(x0), h1=bfh(x1), h2=bfh(x2);
    ushort_t l0=bfh(x0-bff(h0)), l1=bfh(x1-bff(h1)), l2=bfh(x2-bff(h2));
    ushort_t sh=bfh(sx), sl=bfh(sx-bff(sh));
    u.r[0]=h0; u.r[1]=h1; u.r[2]=h2;  u.r[3]=l0; u.r[4]=l1; u.r[5]=l2;
    u.r[6]=h0; u.r[7]=h1; u.r[8]=h2;  u.r[9]=sh; u.r[10]=sl; u.r[11]=ONE; u.r[12]=ONE;
    u.r[13]=0; u.r[14]=0; u.r[15]=0;
    uint4* dst = (uint4*)(Apack + (size_t)idx*16);
    dst[0]=u.q[0]; dst[1]=u.q[1];
  } else {
    int j = idx - NTOTAL;
    int b = j >> 12;
    const float* T = Tm + b*16;
    float y0 = Yv[j*3], y1 = Yv[j*3+1], y2 = Yv[j*3+2];
    // row-vector transform; T[:,3] == [0,0,0,1]^T so w == 1 exactly
    float t0 = y0*T[0] + y1*T[4] + y2*T[8]  + T[12];
    float t1 = y0*T[1] + y1*T[5] + y2*T[9]  + T[13];
    float t2 = y0*T[2] + y1*T[6] + y2*T[10] + T[14];
    float sy = t0*t0 + t1*t1 + t2*t2;
    float z0 = -2.f*t0, z1 = -2.f*t1, z2 = -2.f*t2;
    ushort_t h0=bfh(z0), h1=bfh(z1), h2=bfh(z2);
    ushort_t l0=bfh(z0-bff(h0)), l1=bfh(z1-bff(h1)), l2=bfh(z2-bff(h2));
    ushort_t sh=bfh(sy), sl=bfh(sy-bff(sh));
    u.r[0]=h0; u.r[1]=h1; u.r[2]=h2;  u.r[3]=h0; u.r[4]=h1; u.r[5]=h2;
    u.r[6]=l0; u.r[7]=l1; u.r[8]=l2;  u.r[9]=ONE; u.r[10]=ONE; u.r[11]=sh; u.r[12]=sl;
    u.r[13]=0; u.r[14]=0; u.r[15]=0;
    uint4* dst = (uint4*)(Bpack + (size_t)j*16);
    dst[0]=u.q[0]; dst[1]=u.q[1];
  }
}

// ---------------------------------------------------------------------------
// chamfer_mfma: grid = 16 b x 32 n-chunks. Block = 4 waves x 32 x-rows.
// Each wave iterates ALL m (8 LDS-staged chunks x 16 tiles of 32), one
// mfma_f32_32x32x16_bf16 per 32x32 tile producing full distances.
//  - row-min (over m) accumulates in 16 registers; finalized by 5-step
//    butterfly over lane bits 0..4; clamped, summed, atomicAdd to out.
//  - col-min (over n): 15-op register tree per tile (+clamp), LDS atomicMin
//    (both kh-halves hit the same addr -> free 2-way combine), then one
//    global atomicMin flush per (b,m) at block end.
// D layout (m74/m101 verified): col = lane&31 = B free index.
// ---------------------------------------------------------------------------
__global__ __launch_bounds__(256) void chamfer_mfma(
    const ushort_t* __restrict__ Apack, const ushort_t* __restrict__ Bpack,
    uint_t* __restrict__ colminG, float* __restrict__ out)
{
  __shared__ uint4 Blo[MCHUNK];      // k0..7 halves  (8 KB)
  __shared__ uint4 Bhi[MCHUNK];      // k8..15 halves (8 KB)
  __shared__ uint_t colmin_s[NPTS];  // 16 KB
  __shared__ float blocksum;

  int tid = threadIdx.x, lane = tid & 63, wid = tid >> 6;
  int b = blockIdx.x / NCHUNKS;
  int nchunk = blockIdx.x % NCHUNKS;

  for (int i = tid; i < NPTS; i += 256) colmin_s[i] = 0x7F7F7F7Fu;
  if (tid == 0) blocksum = 0.f;

  int kh = lane >> 5;
  int row = nchunk * ROWS_PER_BLOCK + wid * 32 + (lane & 31);
  bf16x8 afrag = *((const bf16x8*)Apack + ((size_t)b * NPTS + row) * 2 + kh);

  float rm[16];
#pragma unroll
  for (int i = 0; i < 16; i++) rm[i] = 3e38f;

  const bf16x8* bbase_lo = (const bf16x8*)Blo;
  const bf16x8* bbase_hi = (const bf16x8*)Bhi;
  const bf16x8* bbase = kh ? bbase_hi : bbase_lo;

  for (int ch = 0; ch < NMCHUNKS; ++ch) {
    __syncthreads();
    const uint4* src = (const uint4*)(Bpack + ((size_t)b * NPTS + ch * MCHUNK) * 16);
    for (int s = tid; s < MCHUNK; s += 256) {
      Blo[s] = src[2*s];
      Bhi[s] = src[2*s+1];
    }
    __syncthreads();

#pragma unroll 4
    for (int tt = 0; tt < TILES; ++tt) {
      int ml = tt * 32 + (lane & 31);
      bf16x8 bfrag = bbase[ml];
      f32x16 zacc = {};
      f32x16 D = __builtin_amdgcn_mfma_f32_32x32x16_bf16(afrag, bfrag, zacc, 0, 0, 0);
#pragma unroll
      for (int i = 0; i < 16; i++) rm[i] = fminf(rm[i], D[i]);
      float m0 = fminf(fminf(D[0],  D[1]),  D[2]);
      float m1 = fminf(fminf(D[3],  D[4]),  D[5]);
      float m2 = fminf(fminf(D[6],  D[7]),  D[8]);
      float m3 = fminf(fminf(D[9],  D[10]), D[11]);
      float m4 = fminf(fminf(D[12], D[13]), D[14]);
      float cm = fminf(fminf(fminf(m0, m1), m2), fminf(fminf(m3, m4), D[15]));
      atomicMin(&colmin_s[ch * MCHUNK + ml], __float_as_uint(fmaxf(cm, 0.f)));
    }
  }

  // finalize row-mins: butterfly min over lanes within each 32-lane half
#pragma unroll
  for (int s = 1; s <= 16; s <<= 1) {
#pragma unroll
    for (int i = 0; i < 16; i++) rm[i] = fminf(rm[i], __shfl_xor(rm[i], s, 64));
  }
  float rs = 0.f;
#pragma unroll
  for (int i = 0; i < 16; i++) rs += fmaxf(rm[i], 0.f);
  if ((lane & 31) == 0) atomicAdd(&blocksum, rs);   // lanes 0 and 32: the two row-halves
  __syncthreads();
  if (tid == 0) atomicAdd(out, blocksum);
  for (int i = tid; i < NPTS; i += 256)
    atomicMin(&colminG[(size_t)b * NPTS + i], colmin_s[i]);
}

// ---------------------------------------------------------------------------
// colreduce: sum the (already clamped) per-(b,m) col-mins into out.
// ---------------------------------------------------------------------------
__global__ __launch_bounds__(256) void colreduce(
    const uint_t* __restrict__ colminG, float* __restrict__ out)
{
  __shared__ float wsum[4];
  float s = 0.f;
  for (int i = blockIdx.x * 256 + threadIdx.x; i < NTOTAL; i += gridDim.x * 256)
    s += __uint_as_float(colminG[i]);
#pragma unroll
  for (int o = 32; o > 0; o >>= 1) s += __shfl_down(s, o, 64);
  int wid = threadIdx.x >> 6, lane = threadIdx.x & 63;
  if (lane == 0) wsum[wid] = s;
  __syncthreads();
  if (threadIdx.x == 0) {
    float t = wsum[0] + wsum[1] + wsum[2] + wsum[3];
    atomicAdd(out, t);
  }
}

extern "C" void kernel_launch(void* const* d_in, const int* in_sizes, int n_in,
                              void* d_out, int out_size, void* d_ws, size_t ws_size,
                              hipStream_t stream) {
  const float* Xv = (const float*)d_in[0];   // [B,N,3]
  const float* Yv = (const float*)d_in[1];   // [B,M,3]
  const float* Tm = (const float*)d_in[2];   // [B,4,4]
  float* out = (float*)d_out;

  char* ws = (char*)d_ws;
  ushort_t* Apack   = (ushort_t*)ws;                          // 2 MB
  ushort_t* Bpack   = (ushort_t*)(ws + (size_t)2*1024*1024);  // 2 MB
  uint_t*   colminG = (uint_t*)  (ws + (size_t)4*1024*1024);  // 256 KB

  prep<<<(2 * NTOTAL) / 256, 256, 0, stream>>>(Xv, Yv, Tm, Apack, Bpack, colminG, out);
  chamfer_mfma<<<BBATCH * NCHUNKS, 256, 0, stream>>>(Apack, Bpack, colminG, out);
  colreduce<<<64, 256, 0, stream>>>(colminG, out);
}